// Round 2
// baseline (411.002 us; speedup 1.0000x reference)
//
#include <hip/hip_runtime.h>
#include <math.h>

namespace {

constexpr int NB = 8192;   // batch B
constexpr int NE = 4096;   // exemplars E
constexpr int ND = 256;    // dim D
constexpr int NT = 128;    // time T
constexpr int NR = 4;      // risks R
constexpr int NK = 64;     // neighbors K
constexpr int KC = 512;    // concatenated K for split-bf16 GEMM
constexpr int NCAND = 256; // candidate cap per row
constexpr float TAUSQ = 4.0f;
constexpr float FEPS = 1e-12f;
constexpr float QS = 256.0f / 4.5f;   // u8 quantization over [0, 4.5)

typedef short s16x8 __attribute__((ext_vector_type(8)));
typedef float f32x4 __attribute__((ext_vector_type(4)));

__device__ __forceinline__ unsigned short f2bf_rne(float f) {
  unsigned int u = __float_as_uint(f);
  unsigned int r = (u + 0x7FFFu + ((u >> 16) & 1u)) >> 16;
  return (unsigned short)r;
}
__device__ __forceinline__ float bf2f(unsigned short s) {
  return __uint_as_float(((unsigned int)s) << 16);
}

__device__ __forceinline__ void gl_lds16(const void* g, void* lds) {
  __builtin_amdgcn_global_load_lds(
      (const __attribute__((address_space(1))) unsigned int*)g,
      (__attribute__((address_space(3))) unsigned int*)lds, 16, 0, 0);
}

// ---------------- K1: baseline prep (1 block, 128 thr) ----------------
__global__ void k_prep_base(const float* __restrict__ lbev, const float* __restrict__ lbcen,
                            float* __restrict__ bev, float* __restrict__ bar) {
  __shared__ float s[NT];
  int t = threadIdx.x;
  float acc = expf(lbcen[t]);
  for (int r = 0; r < NR; ++r) {
    float v = expf(lbev[t * NR + r]);
    bev[t * NR + r] = v;
    acc += v;
  }
  s[t] = acc;
  __syncthreads();
  float su = 0.f;
  for (int u = t; u < NT; ++u) su += s[u];   // reverse cumsum
  bar[t] = su;
}

// ---------------- K2: EV = exp(log_ev), AR = rev-cumsum (grid E, 128 thr) ----------------
__global__ void k_prep_ev(const float* __restrict__ lev, const float* __restrict__ lcen,
                          float* __restrict__ EV, float* __restrict__ AR) {
  __shared__ float s[NT];
  int e = blockIdx.x, t = threadIdx.x;
  float acc = expf(lcen[(size_t)e * NT + t]);
  const float* src = lev + ((size_t)e * NT + t) * NR;
  float4 o;
  o.x = expf(src[0]); o.y = expf(src[1]); o.z = expf(src[2]); o.w = expf(src[3]);
  *reinterpret_cast<float4*>(EV + ((size_t)e * NT + t) * NR) = o;
  acc += o.x + o.y + o.z + o.w;
  s[t] = acc;
  __syncthreads();
  float su = 0.f;
  for (int u = t; u < NT; ++u) su += s[u];
  AR[(size_t)e * NT + t] = su;
}

// ---------------- K3: split to bf16 hi/lo + row norms (grid B+E, 1 wave) ----------------
// Xcat = [xhi | xlo]  (K=512),  Ecat = [ehi | ehi]
__global__ void k_split(const float* __restrict__ x, const float* __restrict__ ex,
                        unsigned short* __restrict__ xcat, unsigned short* __restrict__ ecat,
                        float* __restrict__ xn, float* __restrict__ exn) {
  int row = blockIdx.x, l = threadIdx.x;  // 64 threads, 4 floats each
  bool isx = row < NB;
  const float* p = isx ? (x + (size_t)row * ND) : (ex + (size_t)(row - NB) * ND);
  unsigned short* dst = isx ? (xcat + (size_t)row * KC) : (ecat + (size_t)(row - NB) * KC);
  float4 v = reinterpret_cast<const float4*>(p)[l];
  float nv = v.x * v.x + v.y * v.y + v.z * v.z + v.w * v.w;
  float vf[4] = {v.x, v.y, v.z, v.w};
  ushort4 hi4, lo4;
  unsigned short* hp = &hi4.x;
  unsigned short* lp = &lo4.x;
  #pragma unroll
  for (int i = 0; i < 4; ++i) {
    unsigned short h = f2bf_rne(vf[i]);
    hp[i] = h;
    lp[i] = f2bf_rne(vf[i] - bf2f(h));
  }
  *reinterpret_cast<ushort4*>(dst + l * 4) = hi4;
  *reinterpret_cast<ushort4*>(dst + ND + l * 4) = isx ? lo4 : hi4;
  for (int o = 32; o > 0; o >>= 1) nv += __shfl_down(nv, o);
  if (l == 0) { if (isx) xn[row] = nv; else exn[row - NB] = nv; }
}

// ---------------- K4: bf16 MFMA distance GEMM -> u8 bins ----------------
// 128x128 tile, 4 waves (2x2), 16x16x32 bf16 MFMA, global_load_lds + XOR swizzle.
__global__ __launch_bounds__(256) void k_dist_mfma(
    const unsigned short* __restrict__ xcat, const unsigned short* __restrict__ ecat,
    const float* __restrict__ xn, const float* __restrict__ exn,
    unsigned char* __restrict__ d2q) {
  __shared__ __align__(16) unsigned char As[128 * 64];  // 128 rows x 32 bf16 (64 B/row)
  __shared__ __align__(16) unsigned char Bs[128 * 64];
  int tid = threadIdx.x;
  int l = tid & 63, w = tid >> 6;
  int wr = w >> 1, wc = w & 1;
  int nb = blockIdx.x * 128, mb = blockIdx.y * 128;

  f32x4 acc[4][4];
  #pragma unroll
  for (int m = 0; m < 4; ++m)
    #pragma unroll
    for (int n = 0; n < 4; ++n)
      acc[m][n] = (f32x4){0.f, 0.f, 0.f, 0.f};

  for (int k0 = 0; k0 < KC; k0 += 32) {
    // stage: 512 chunks of 16 B per tile; chunk c -> row=c>>2, lds-slot=c&3.
    // linear LDS dest + pre-swizzled global source (slot ^ swz(row))
    #pragma unroll
    for (int h = 0; h < 2; ++h) {
      int c = h * 256 + tid;              // = (h*256 + w*64) + l  -> wave-uniform base + l*16
      int row = c >> 2, slot = c & 3;
      int swz = (row ^ (row >> 2)) & 3;
      int gcol = k0 + ((slot ^ swz) << 3);
      gl_lds16(xcat + (size_t)(mb + row) * KC + gcol, As + c * 16);
      gl_lds16(ecat + (size_t)(nb + row) * KC + gcol, Bs + c * 16);
    }
    __syncthreads();
    s16x8 af[4], bf_[4];
    int ko = l >> 4;
    #pragma unroll
    for (int m = 0; m < 4; ++m) {
      int r = wr * 64 + m * 16 + (l & 15);
      int swz = (r ^ (r >> 2)) & 3;
      af[m] = *(const s16x8*)(As + r * 64 + ((ko ^ swz) << 4));
    }
    #pragma unroll
    for (int n = 0; n < 4; ++n) {
      int r = wc * 64 + n * 16 + (l & 15);
      int swz = (r ^ (r >> 2)) & 3;
      bf_[n] = *(const s16x8*)(Bs + r * 64 + ((ko ^ swz) << 4));
    }
    #pragma unroll
    for (int m = 0; m < 4; ++m)
      #pragma unroll
      for (int n = 0; n < 4; ++n)
        acc[m][n] = __builtin_amdgcn_mfma_f32_16x16x32_bf16(af[m], bf_[n], acc[m][n], 0, 0, 0);
    __syncthreads();
  }

  // epilogue: d2 = xn + exn - 2*dot, quantize u8.  C-map: row=(l>>4)*4+j, col=l&15
  int col0 = nb + wc * 64 + (l & 15);
  int row0 = mb + wr * 64 + (l >> 4) * 4;
  float exnv[4];
  #pragma unroll
  for (int n = 0; n < 4; ++n) exnv[n] = exn[col0 + n * 16];
  #pragma unroll
  for (int m = 0; m < 4; ++m) {
    #pragma unroll
    for (int j = 0; j < 4; ++j) {
      int qrow = row0 + m * 16 + j;
      float xq = xn[qrow];
      #pragma unroll
      for (int n = 0; n < 4; ++n) {
        float d2 = xq + exnv[n] - 2.f * acc[m][n][j];
        int bin = (int)floorf(d2 * QS);
        bin = bin < 0 ? 0 : (bin > 255 ? 255 : bin);
        d2q[(size_t)qrow * NE + (col0 + n * 16)] = (unsigned char)bin;
      }
    }
  }
}

// ---------------- K5: exact top-K via histogram-select (+1-bin guard) ----------------
// 4 rows/block (one per wave).
__global__ __launch_bounds__(256) void k_select(const unsigned char* __restrict__ d2q,
                                                const float* __restrict__ x, const float* __restrict__ ex,
                                                const float* __restrict__ xn, const float* __restrict__ exn,
                                                float* __restrict__ selw, int* __restrict__ seli) {
  __shared__ unsigned int hist[4][256];
  __shared__ int cnt[4];
  __shared__ int cand_e[4][NCAND];
  __shared__ float cand_d[4][NCAND];
  int tid = threadIdx.x;
  int wid = tid >> 6, l = tid & 63;
  int b = blockIdx.x * 4 + wid;

  for (int i = tid; i < 4 * 256; i += 256) (&hist[0][0])[i] = 0u;
  if (l == 0) cnt[wid] = 0;
  __syncthreads();

  // load the u8 row (4096 B) into registers, coalesced
  uint4 wb[4];
  const uint4* rp = reinterpret_cast<const uint4*>(d2q + (size_t)b * NE);
  #pragma unroll
  for (int p = 0; p < 4; ++p) wb[p] = rp[p * 64 + l];

  // histogram
  #pragma unroll
  for (int p = 0; p < 4; ++p) {
    unsigned int wq[4] = {wb[p].x, wb[p].y, wb[p].z, wb[p].w};
    #pragma unroll
    for (int c = 0; c < 4; ++c)
      #pragma unroll
      for (int by = 0; by < 4; ++by)
        atomicAdd(&hist[wid][(wq[c] >> (8 * by)) & 255u], 1u);
  }
  __syncthreads();

  // smallest bin with cumulative count >= K, then +1 guard band
  int cb = 255;
  unsigned int cum = 0;
  for (int bin = 0; bin < 256; ++bin) {
    cum += hist[wid][bin];
    if (cum >= (unsigned)NK) { cb = bin; break; }
  }
  cb = cb < 255 ? cb + 1 : 255;

  // collect candidates (bin <= cb)
  #pragma unroll
  for (int p = 0; p < 4; ++p) {
    unsigned int wq[4] = {wb[p].x, wb[p].y, wb[p].z, wb[p].w};
    #pragma unroll
    for (int c = 0; c < 4; ++c)
      #pragma unroll
      for (int by = 0; by < 4; ++by) {
        int bin = (int)((wq[c] >> (8 * by)) & 255u);
        if (bin <= cb) {
          int pos = atomicAdd(&cnt[wid], 1);
          if (pos < NCAND) cand_e[wid][pos] = ((p * 64 + l) * 4 + c) * 4 + by;
        }
      }
  }
  __syncthreads();

  int nc = cnt[wid]; if (nc > NCAND) nc = NCAND;

  // exact fp32 d2 per candidate (wave-cooperative dot)
  float4 xv = reinterpret_cast<const float4*>(x + (size_t)b * ND)[l];
  float bxn = xn[b];
  for (int cix = 0; cix < nc; ++cix) {
    int e = cand_e[wid][cix];
    float4 ev = reinterpret_cast<const float4*>(ex + (size_t)e * ND)[l];
    float sv = xv.x * ev.x + xv.y * ev.y + xv.z * ev.z + xv.w * ev.w;
    for (int o = 32; o > 0; o >>= 1) sv += __shfl_down(sv, o);
    if (l == 0) cand_d[wid][cix] = bxn + exn[e] - 2.f * sv;
  }
  __syncthreads();

  // exact rank among candidates (stable); emit exp(-d2) weights for ranks < K
  for (int i = l; i < nc; i += 64) {
    float di = cand_d[wid][i];
    int rank = 0;
    for (int j = 0; j < nc; ++j) {
      float dj = cand_d[wid][j];
      rank += (dj < di) || (dj == di && j < i);
    }
    if (rank < NK) {
      float sq = fmaxf(di, 0.f);
      float wgt = (sq <= TAUSQ) ? expf(-sq) : 0.f;
      selw[(size_t)b * NK + rank] = wgt;
      seli[(size_t)b * NK + rank] = cand_e[wid][i];
    }
  }
  if (l >= nc && l < NK) {   // degenerate-safety fill
    selw[(size_t)b * NK + l] = 0.f;
    seli[(size_t)b * NK + l] = 0;
  }
}

// ---------------- K6: gather-accumulate numer/denom, write hazards ----------------
__global__ __launch_bounds__(256) void k_out(const float* __restrict__ EV, const float* __restrict__ AR,
                                             const float* __restrict__ bev, const float* __restrict__ bar,
                                             const float* __restrict__ selw, const int* __restrict__ seli,
                                             float* __restrict__ out) {
  __shared__ float wl[NK];
  __shared__ int il[NK];
  __shared__ float den[NT];
  __shared__ float num[NT * NR];
  int tid = threadIdx.x;
  int b = blockIdx.x;
  if (tid < NK) { wl[tid] = selw[(size_t)b * NK + tid]; il[tid] = seli[(size_t)b * NK + tid]; }
  __syncthreads();
  float n0 = 0.f, n1 = 0.f, dn = 0.f;
  for (int k = 0; k < NK; ++k) {
    float wgt = wl[k];
    int e = il[k];
    const float* evp = EV + (size_t)e * (NT * NR);
    n0 += wgt * evp[tid];
    n1 += wgt * evp[256 + tid];
    if (tid < NT) dn += wgt * AR[(size_t)e * NT + tid];   // wave-uniform predicate
  }
  n0 += bev[tid];
  n1 += bev[256 + tid];
  num[tid] = n0; num[256 + tid] = n1;
  if (tid < NT) den[tid] = dn + bar[tid] + FEPS;
  __syncthreads();
  const float lo = FEPS, hi = 1.0f - FEPS;
  {
    int t = tid >> 2, r = tid & 3;                 // EV layout: f = t*4 + r
    float h = n0 / den[t];
    h = fminf(fmaxf(h, lo), hi);
    out[((size_t)r * NB + b) * NT + t] = h;        // esh[r][b][t]
    int f1 = tid + 256;
    int t1 = f1 >> 2, r1 = f1 & 3;
    float h1 = n1 / den[t1];
    h1 = fminf(fmaxf(h1, lo), hi);
    out[((size_t)r1 * NB + b) * NT + t1] = h1;
  }
  if (tid < NT) {
    float sum = num[4 * tid] + num[4 * tid + 1] + num[4 * tid + 2] + num[4 * tid + 3];
    float ov = sum / den[tid];
    ov = fminf(fmaxf(ov, lo), hi);
    out[(size_t)4 * NB * NT + (size_t)b * NT + tid] = ov;   // overall[b][t]
  }
}

} // namespace

extern "C" void kernel_launch(void* const* d_in, const int* in_sizes, int n_in,
                              void* d_out, int out_size, void* d_ws, size_t ws_size,
                              hipStream_t stream) {
  (void)in_sizes; (void)n_in; (void)out_size; (void)ws_size;
  const float* x     = (const float*)d_in[0];
  const float* ex    = (const float*)d_in[1];
  const float* lev   = (const float*)d_in[2];
  const float* lcen  = (const float*)d_in[3];
  const float* lbev  = (const float*)d_in[4];
  const float* lbcen = (const float*)d_in[5];
  float* out = (float*)d_out;

  // workspace layout (~59 MiB)
  char* ws = (char*)d_ws;
  float* EV  = (float*)(ws);                                      // [E][T][R]  8 MiB
  float* AR  = (float*)(ws + (8ull << 20));                       // [E][T]     2 MiB
  float* bev = (float*)(ws + (10ull << 20));                      // [T][R]
  float* bar = (float*)(ws + (10ull << 20) + 4096);               // [T]
  float* exn = (float*)(ws + (10ull << 20) + 8192);               // [E]
  float* xn  = (float*)(ws + (10ull << 20) + 8192 + (16u << 10)); // [B]
  unsigned char* d2q = (unsigned char*)(ws + (11ull << 20));      // [B][E] u8  32 MiB
  float* selw = (float*)(ws + (43ull << 20));                     // [B][K]     2 MiB
  int*   seli = (int*)  (ws + (45ull << 20));                     // [B][K]     2 MiB
  unsigned short* xcat = (unsigned short*)(ws + (47ull << 20));   // [B][KC]    8 MiB
  unsigned short* ecat = (unsigned short*)(ws + (55ull << 20));   // [E][KC]    4 MiB

  k_prep_base<<<1, NT, 0, stream>>>(lbev, lbcen, bev, bar);
  k_prep_ev<<<NE, NT, 0, stream>>>(lev, lcen, EV, AR);
  k_split<<<NB + NE, 64, 0, stream>>>(x, ex, xcat, ecat, xn, exn);
  k_dist_mfma<<<dim3(NE / 128, NB / 128), 256, 0, stream>>>(xcat, ecat, xn, exn, d2q);
  k_select<<<NB / 4, 256, 0, stream>>>(d2q, x, ex, xn, exn, selw, seli);
  k_out<<<NB, 256, 0, stream>>>(EV, AR, bev, bar, selw, seli, out);
}

// Round 3
// 373.769 us; speedup vs baseline: 1.0996x; 1.0996x over previous
//
#include <hip/hip_runtime.h>
#include <math.h>

namespace {

constexpr int NB = 8192;   // batch B
constexpr int NE = 4096;   // exemplars E
constexpr int ND = 256;    // dim D
constexpr int NT = 128;    // time T
constexpr int NR = 4;      // risks R
constexpr int NK = 64;     // neighbors K
constexpr int NCAND = 320; // candidate cap per row
constexpr float TAUSQ = 4.0f;
constexpr float FEPS = 1e-12f;
constexpr float QS = 256.0f / 4.5f;   // u8 quantization over [0, 4.5)

typedef short s16x8 __attribute__((ext_vector_type(8)));
typedef float f32x4 __attribute__((ext_vector_type(4)));

__device__ __forceinline__ unsigned short f2bf_rne(float f) {
  unsigned int u = __float_as_uint(f);
  unsigned int r = (u + 0x7FFFu + ((u >> 16) & 1u)) >> 16;
  return (unsigned short)r;
}

__device__ __forceinline__ void gl_lds16(const void* g, void* lds) {
  __builtin_amdgcn_global_load_lds(
      (const __attribute__((address_space(1))) unsigned int*)g,
      (__attribute__((address_space(3))) unsigned int*)lds, 16, 0, 0);
}

// ---------------- K1: baseline prep (1 block, 128 thr) ----------------
__global__ void k_prep_base(const float* __restrict__ lbev, const float* __restrict__ lbcen,
                            float* __restrict__ bev, float* __restrict__ bar) {
  __shared__ float s[NT];
  int t = threadIdx.x;
  float acc = expf(lbcen[t]);
  for (int r = 0; r < NR; ++r) {
    float v = expf(lbev[t * NR + r]);
    bev[t * NR + r] = v;
    acc += v;
  }
  s[t] = acc;
  __syncthreads();
  float su = 0.f;
  for (int u = t; u < NT; ++u) su += s[u];   // reverse cumsum
  bar[t] = su;
}

// ---------------- K2: EV = exp(log_ev), AR = rev-cumsum (grid E, 128 thr) ----------------
__global__ void k_prep_ev(const float* __restrict__ lev, const float* __restrict__ lcen,
                          float* __restrict__ EV, float* __restrict__ AR) {
  __shared__ float s[NT];
  int e = blockIdx.x, t = threadIdx.x;
  float acc = expf(lcen[(size_t)e * NT + t]);
  const float* src = lev + ((size_t)e * NT + t) * NR;
  float4 o;
  o.x = expf(src[0]); o.y = expf(src[1]); o.z = expf(src[2]); o.w = expf(src[3]);
  *reinterpret_cast<float4*>(EV + ((size_t)e * NT + t) * NR) = o;
  acc += o.x + o.y + o.z + o.w;
  s[t] = acc;
  __syncthreads();
  float su = 0.f;
  for (int u = t; u < NT; ++u) su += s[u];
  AR[(size_t)e * NT + t] = su;
}

// ---------------- K3: bf16 convert + row norms (grid B+E, 1 wave) ----------------
__global__ void k_split(const float* __restrict__ x, const float* __restrict__ ex,
                        unsigned short* __restrict__ xh, unsigned short* __restrict__ eh,
                        float* __restrict__ xn, float* __restrict__ exn) {
  int row = blockIdx.x, l = threadIdx.x;  // 64 threads, 4 floats each
  bool isx = row < NB;
  const float* p = isx ? (x + (size_t)row * ND) : (ex + (size_t)(row - NB) * ND);
  unsigned short* dst = isx ? (xh + (size_t)row * ND) : (eh + (size_t)(row - NB) * ND);
  float4 v = reinterpret_cast<const float4*>(p)[l];
  float nv = v.x * v.x + v.y * v.y + v.z * v.z + v.w * v.w;
  ushort4 h4;
  h4.x = f2bf_rne(v.x); h4.y = f2bf_rne(v.y);
  h4.z = f2bf_rne(v.z); h4.w = f2bf_rne(v.w);
  reinterpret_cast<ushort4*>(dst)[l] = h4;
  for (int o = 32; o > 0; o >>= 1) nv += __shfl_down(nv, o);
  if (l == 0) { if (isx) xn[row] = nv; else exn[row - NB] = nv; }
}

// ---------------- K4: bf16 MFMA distance GEMM (K=256) -> u8 bins ----------------
// 128x128 tile, 4 waves (2x2), 16x16x32 bf16 MFMA, global_load_lds + XOR swizzle.
__global__ __launch_bounds__(256) void k_dist_mfma(
    const unsigned short* __restrict__ xh, const unsigned short* __restrict__ eh,
    const float* __restrict__ xn, const float* __restrict__ exn,
    unsigned char* __restrict__ d2q) {
  __shared__ __align__(16) unsigned char As[128 * 64];  // 128 rows x 32 bf16 (64 B/row)
  __shared__ __align__(16) unsigned char Bs[128 * 64];
  int tid = threadIdx.x;
  int l = tid & 63, w = tid >> 6;
  int wr = w >> 1, wc = w & 1;
  int nb = blockIdx.x * 128, mb = blockIdx.y * 128;

  f32x4 acc[4][4];
  #pragma unroll
  for (int m = 0; m < 4; ++m)
    #pragma unroll
    for (int n = 0; n < 4; ++n)
      acc[m][n] = (f32x4){0.f, 0.f, 0.f, 0.f};

  for (int k0 = 0; k0 < ND; k0 += 32) {
    // stage: 512 chunks of 16 B per tile; chunk c -> row=c>>2, lds-slot=c&3.
    // linear LDS dest + pre-swizzled global source (slot ^ swz(row))
    #pragma unroll
    for (int h = 0; h < 2; ++h) {
      int c = h * 256 + tid;              // wave-uniform base + l*16
      int row = c >> 2, slot = c & 3;
      int swz = (row ^ (row >> 2)) & 3;
      int gcol = k0 + ((slot ^ swz) << 3);
      gl_lds16(xh + (size_t)(mb + row) * ND + gcol, As + c * 16);
      gl_lds16(eh + (size_t)(nb + row) * ND + gcol, Bs + c * 16);
    }
    __syncthreads();
    s16x8 af[4], bf_[4];
    int ko = l >> 4;
    #pragma unroll
    for (int m = 0; m < 4; ++m) {
      int r = wr * 64 + m * 16 + (l & 15);
      int swz = (r ^ (r >> 2)) & 3;
      af[m] = *(const s16x8*)(As + r * 64 + ((ko ^ swz) << 4));
    }
    #pragma unroll
    for (int n = 0; n < 4; ++n) {
      int r = wc * 64 + n * 16 + (l & 15);
      int swz = (r ^ (r >> 2)) & 3;
      bf_[n] = *(const s16x8*)(Bs + r * 64 + ((ko ^ swz) << 4));
    }
    #pragma unroll
    for (int m = 0; m < 4; ++m)
      #pragma unroll
      for (int n = 0; n < 4; ++n)
        acc[m][n] = __builtin_amdgcn_mfma_f32_16x16x32_bf16(af[m], bf_[n], acc[m][n], 0, 0, 0);
    __syncthreads();
  }

  // epilogue: d2 = xn + exn - 2*dot, quantize u8.  C-map: row=(l>>4)*4+j, col=l&15
  int col0 = nb + wc * 64 + (l & 15);
  int row0 = mb + wr * 64 + (l >> 4) * 4;
  float exnv[4];
  #pragma unroll
  for (int n = 0; n < 4; ++n) exnv[n] = exn[col0 + n * 16];
  #pragma unroll
  for (int m = 0; m < 4; ++m) {
    #pragma unroll
    for (int j = 0; j < 4; ++j) {
      int qrow = row0 + m * 16 + j;
      float xq = xn[qrow];
      #pragma unroll
      for (int n = 0; n < 4; ++n) {
        float d2 = xq + exnv[n] - 2.f * acc[m][n][j];
        int bin = (int)floorf(d2 * QS);
        bin = bin < 0 ? 0 : (bin > 255 ? 255 : bin);
        d2q[(size_t)qrow * NE + (col0 + n * 16)] = (unsigned char)bin;
      }
    }
  }
}

// count of bytes <= t over the wave's 4096-byte row (wb = 64 B per lane), broadcast to all lanes
__device__ __forceinline__ int wave_count_le(const uint4 (&wb)[4], int t) {
  int c = 0;
  #pragma unroll
  for (int p = 0; p < 4; ++p) {
    unsigned int wq[4] = {wb[p].x, wb[p].y, wb[p].z, wb[p].w};
    #pragma unroll
    for (int cc = 0; cc < 4; ++cc)
      #pragma unroll
      for (int by = 0; by < 4; ++by)
        c += ((int)((wq[cc] >> (8 * by)) & 255u) <= t) ? 1 : 0;
  }
  for (int o = 32; o > 0; o >>= 1) c += __shfl_down(c, o);
  return __shfl(c, 0);
}

// ---------------- K5: exact top-K: binary-search threshold + per-lane exact dots ----------------
// 4 rows/block (one wave each).
__global__ __launch_bounds__(256) void k_select(const unsigned char* __restrict__ d2q,
                                                const float* __restrict__ x, const float* __restrict__ ex,
                                                const float* __restrict__ xn, const float* __restrict__ exn,
                                                float* __restrict__ selw, int* __restrict__ seli) {
  __shared__ float4 xs[4][64];          // x row per wave
  __shared__ int cnt[4];
  __shared__ int cand_e[4][NCAND];
  __shared__ float cand_d[4][NCAND];
  int tid = threadIdx.x;
  int wid = tid >> 6, l = tid & 63;
  int b = blockIdx.x * 4 + wid;

  // load the u8 row (4096 B) into registers, coalesced
  uint4 wb[4];
  const uint4* rp = reinterpret_cast<const uint4*>(d2q + (size_t)b * NE);
  #pragma unroll
  for (int p = 0; p < 4; ++p) wb[p] = rp[p * 64 + l];

  // stage x row for the dot phase; init counter
  xs[wid][l] = reinterpret_cast<const float4*>(x + (size_t)b * ND)[l];
  if (l == 0) cnt[wid] = 0;

  // binary search: smallest cb with count(<= cb) >= K  (register-only, no atomics)
  int base = 0;
  #pragma unroll
  for (int bit = 128; bit; bit >>= 1) {
    int t = base + bit - 1;
    if (wave_count_le(wb, t) < NK) base += bit;
  }
  int cbg = base < 255 ? base + 1 : 255;   // +1-bin guard band

  __syncthreads();

  // collect candidates (bin <= cbg); sparse (~90/row) LDS atomics
  #pragma unroll
  for (int p = 0; p < 4; ++p) {
    unsigned int wq[4] = {wb[p].x, wb[p].y, wb[p].z, wb[p].w};
    #pragma unroll
    for (int cc = 0; cc < 4; ++cc)
      #pragma unroll
      for (int by = 0; by < 4; ++by) {
        int bin = (int)((wq[cc] >> (8 * by)) & 255u);
        if (bin <= cbg) {
          int pos = atomicAdd(&cnt[wid], 1);
          if (pos < NCAND) cand_e[wid][pos] = ((p * 64 + l) * 4 + cc) * 4 + by;
        }
      }
  }
  __syncthreads();

  int nc = cnt[wid]; if (nc > NCAND) nc = NCAND;

  // exact fp32 d2 per candidate: one candidate per lane, full-row dot (pipelined L2 loads)
  float bxn = xn[b];
  for (int ci = l; ci < nc; ci += 64) {
    int e = cand_e[wid][ci];
    const float4* ep = reinterpret_cast<const float4*>(ex + (size_t)e * ND);
    float s = 0.f;
    #pragma unroll 16
    for (int q = 0; q < 64; ++q) {
      float4 xv = xs[wid][q];     // LDS broadcast
      float4 evq = ep[q];
      s += xv.x * evq.x + xv.y * evq.y + xv.z * evq.z + xv.w * evq.w;
    }
    cand_d[wid][ci] = bxn + exn[e] - 2.f * s;
  }
  __syncthreads();

  // exact rank among candidates (tie-break by exemplar index, = top_k semantics)
  for (int i = l; i < nc; i += 64) {
    float di = cand_d[wid][i];
    int ei = cand_e[wid][i];
    int rank = 0;
    for (int j = 0; j < nc; ++j) {
      float dj = cand_d[wid][j];
      rank += (dj < di) || (dj == di && cand_e[wid][j] < ei);
    }
    if (rank < NK) {
      float sq = fmaxf(di, 0.f);
      float wgt = (sq <= TAUSQ) ? expf(-sq) : 0.f;
      selw[(size_t)b * NK + rank] = wgt;
      seli[(size_t)b * NK + rank] = ei;
    }
  }
  if (l >= nc && l < NK) {   // degenerate-safety fill
    selw[(size_t)b * NK + l] = 0.f;
    seli[(size_t)b * NK + l] = 0;
  }
}

// ---------------- K6: gather-accumulate numer/denom, write hazards ----------------
__global__ __launch_bounds__(256) void k_out(const float* __restrict__ EV, const float* __restrict__ AR,
                                             const float* __restrict__ bev, const float* __restrict__ bar,
                                             const float* __restrict__ selw, const int* __restrict__ seli,
                                             float* __restrict__ out) {
  __shared__ float wl[NK];
  __shared__ int il[NK];
  __shared__ float den[NT];
  __shared__ float num[NT * NR];
  int tid = threadIdx.x;
  int b = blockIdx.x;
  if (tid < NK) { wl[tid] = selw[(size_t)b * NK + tid]; il[tid] = seli[(size_t)b * NK + tid]; }
  __syncthreads();
  float n0 = 0.f, n1 = 0.f, dn = 0.f;
  for (int k = 0; k < NK; ++k) {
    float wgt = wl[k];
    int e = il[k];
    const float* evp = EV + (size_t)e * (NT * NR);
    n0 += wgt * evp[tid];
    n1 += wgt * evp[256 + tid];
    if (tid < NT) dn += wgt * AR[(size_t)e * NT + tid];   // wave-uniform predicate
  }
  n0 += bev[tid];
  n1 += bev[256 + tid];
  num[tid] = n0; num[256 + tid] = n1;
  if (tid < NT) den[tid] = dn + bar[tid] + FEPS;
  __syncthreads();
  const float lo = FEPS, hi = 1.0f - FEPS;
  {
    int t = tid >> 2, r = tid & 3;                 // EV layout: f = t*4 + r
    float h = n0 / den[t];
    h = fminf(fmaxf(h, lo), hi);
    out[((size_t)r * NB + b) * NT + t] = h;        // esh[r][b][t]
    int f1 = tid + 256;
    int t1 = f1 >> 2, r1 = f1 & 3;
    float h1 = n1 / den[t1];
    h1 = fminf(fmaxf(h1, lo), hi);
    out[((size_t)r1 * NB + b) * NT + t1] = h1;
  }
  if (tid < NT) {
    float sum = num[4 * tid] + num[4 * tid + 1] + num[4 * tid + 2] + num[4 * tid + 3];
    float ov = sum / den[tid];
    ov = fminf(fmaxf(ov, lo), hi);
    out[(size_t)4 * NB * NT + (size_t)b * NT + tid] = ov;   // overall[b][t]
  }
}

} // namespace

extern "C" void kernel_launch(void* const* d_in, const int* in_sizes, int n_in,
                              void* d_out, int out_size, void* d_ws, size_t ws_size,
                              hipStream_t stream) {
  (void)in_sizes; (void)n_in; (void)out_size; (void)ws_size;
  const float* x     = (const float*)d_in[0];
  const float* ex    = (const float*)d_in[1];
  const float* lev   = (const float*)d_in[2];
  const float* lcen  = (const float*)d_in[3];
  const float* lbev  = (const float*)d_in[4];
  const float* lbcen = (const float*)d_in[5];
  float* out = (float*)d_out;

  // workspace layout (~53 MiB)
  char* ws = (char*)d_ws;
  float* EV  = (float*)(ws);                                      // [E][T][R]  8 MiB
  float* AR  = (float*)(ws + (8ull << 20));                       // [E][T]     2 MiB
  float* bev = (float*)(ws + (10ull << 20));                      // [T][R]
  float* bar = (float*)(ws + (10ull << 20) + 4096);               // [T]
  float* exn = (float*)(ws + (10ull << 20) + 8192);               // [E]
  float* xn  = (float*)(ws + (10ull << 20) + 8192 + (16u << 10)); // [B]
  unsigned char* d2q = (unsigned char*)(ws + (11ull << 20));      // [B][E] u8  32 MiB
  float* selw = (float*)(ws + (43ull << 20));                     // [B][K]     2 MiB
  int*   seli = (int*)  (ws + (45ull << 20));                     // [B][K]     2 MiB
  unsigned short* xh = (unsigned short*)(ws + (47ull << 20));     // [B][D] bf16 4 MiB
  unsigned short* eh = (unsigned short*)(ws + (51ull << 20));     // [E][D] bf16 2 MiB

  k_prep_base<<<1, NT, 0, stream>>>(lbev, lbcen, bev, bar);
  k_prep_ev<<<NE, NT, 0, stream>>>(lev, lcen, EV, AR);
  k_split<<<NB + NE, 64, 0, stream>>>(x, ex, xh, eh, xn, exn);
  k_dist_mfma<<<dim3(NE / 128, NB / 128), 256, 0, stream>>>(xh, eh, xn, exn, d2q);
  k_select<<<NB / 4, 256, 0, stream>>>(d2q, x, ex, xn, exn, selw, seli);
  k_out<<<NB, 256, 0, stream>>>(EV, AR, bev, bar, selw, seli, out);
}

// Round 4
// 280.047 us; speedup vs baseline: 1.4676x; 1.3347x over previous
//
#include <hip/hip_runtime.h>
#include <math.h>

namespace {

constexpr int NB = 8192;   // batch B
constexpr int NE = 4096;   // exemplars E
constexpr int ND = 256;    // dim D
constexpr int NT = 128;    // time T
constexpr int NR = 4;      // risks R
constexpr int NK = 64;     // neighbors K
constexpr int NCAND = 320; // candidate cap per row
constexpr float TAUSQ = 4.0f;
constexpr float FEPS = 1e-12f;
constexpr float QS = 256.0f / 4.5f;   // u8 quantization over [0, 4.5)

typedef short s16x8 __attribute__((ext_vector_type(8)));
typedef float f32x4 __attribute__((ext_vector_type(4)));

__device__ __forceinline__ unsigned short f2bf_rne(float f) {
  unsigned int u = __float_as_uint(f);
  unsigned int r = (u + 0x7FFFu + ((u >> 16) & 1u)) >> 16;
  return (unsigned short)r;
}

__device__ __forceinline__ void gl_lds16(const void* g, void* lds) {
  __builtin_amdgcn_global_load_lds(
      (const __attribute__((address_space(1))) unsigned int*)g,
      (__attribute__((address_space(3))) unsigned int*)lds, 16, 0, 0);
}

// ---------------- K1: baseline prep (1 block, 128 thr) ----------------
__global__ void k_prep_base(const float* __restrict__ lbev, const float* __restrict__ lbcen,
                            float* __restrict__ bev, float* __restrict__ bar) {
  __shared__ float s[NT];
  int t = threadIdx.x;
  float acc = expf(lbcen[t]);
  for (int r = 0; r < NR; ++r) {
    float v = expf(lbev[t * NR + r]);
    bev[t * NR + r] = v;
    acc += v;
  }
  s[t] = acc;
  __syncthreads();
  float su = 0.f;
  for (int u = t; u < NT; ++u) su += s[u];   // reverse cumsum
  bar[t] = su;
}

// ---------------- K2: EV = exp(log_ev), AR = rev-cumsum (grid E, 128 thr) ----------------
__global__ void k_prep_ev(const float* __restrict__ lev, const float* __restrict__ lcen,
                          float* __restrict__ EV, float* __restrict__ AR) {
  __shared__ float s[NT];
  int e = blockIdx.x, t = threadIdx.x;
  float acc = expf(lcen[(size_t)e * NT + t]);
  const float* src = lev + ((size_t)e * NT + t) * NR;
  float4 o;
  o.x = expf(src[0]); o.y = expf(src[1]); o.z = expf(src[2]); o.w = expf(src[3]);
  *reinterpret_cast<float4*>(EV + ((size_t)e * NT + t) * NR) = o;
  acc += o.x + o.y + o.z + o.w;
  s[t] = acc;
  __syncthreads();
  float su = 0.f;
  for (int u = t; u < NT; ++u) su += s[u];
  AR[(size_t)e * NT + t] = su;
}

// ---------------- K3: bf16 convert + row norms (grid B+E, 1 wave) ----------------
__global__ void k_split(const float* __restrict__ x, const float* __restrict__ ex,
                        unsigned short* __restrict__ xh, unsigned short* __restrict__ eh,
                        float* __restrict__ xn, float* __restrict__ exn) {
  int row = blockIdx.x, l = threadIdx.x;  // 64 threads, 4 floats each
  bool isx = row < NB;
  const float* p = isx ? (x + (size_t)row * ND) : (ex + (size_t)(row - NB) * ND);
  unsigned short* dst = isx ? (xh + (size_t)row * ND) : (eh + (size_t)(row - NB) * ND);
  float4 v = reinterpret_cast<const float4*>(p)[l];
  float nv = v.x * v.x + v.y * v.y + v.z * v.z + v.w * v.w;
  ushort4 h4;
  h4.x = f2bf_rne(v.x); h4.y = f2bf_rne(v.y);
  h4.z = f2bf_rne(v.z); h4.w = f2bf_rne(v.w);
  reinterpret_cast<ushort4*>(dst)[l] = h4;
  for (int o = 32; o > 0; o >>= 1) nv += __shfl_down(nv, o);
  if (l == 0) { if (isx) xn[row] = nv; else exn[row - NB] = nv; }
}

// ---------------- K4: bf16 MFMA distance GEMM (K=256) -> u8 bins ----------------
// 128x128 tile, 4 waves (2x2), 16x16x32 bf16 MFMA, global_load_lds + XOR swizzle.
__global__ __launch_bounds__(256) void k_dist_mfma(
    const unsigned short* __restrict__ xh, const unsigned short* __restrict__ eh,
    const float* __restrict__ xn, const float* __restrict__ exn,
    unsigned char* __restrict__ d2q) {
  __shared__ __align__(16) unsigned char As[128 * 64];  // 128 rows x 32 bf16 (64 B/row)
  __shared__ __align__(16) unsigned char Bs[128 * 64];
  int tid = threadIdx.x;
  int l = tid & 63, w = tid >> 6;
  int wr = w >> 1, wc = w & 1;
  int nb = blockIdx.x * 128, mb = blockIdx.y * 128;

  f32x4 acc[4][4];
  #pragma unroll
  for (int m = 0; m < 4; ++m)
    #pragma unroll
    for (int n = 0; n < 4; ++n)
      acc[m][n] = (f32x4){0.f, 0.f, 0.f, 0.f};

  for (int k0 = 0; k0 < ND; k0 += 32) {
    // stage: 512 chunks of 16 B per tile; chunk c -> row=c>>2, lds-slot=c&3.
    // linear LDS dest + pre-swizzled global source (slot ^ swz(row))
    #pragma unroll
    for (int h = 0; h < 2; ++h) {
      int c = h * 256 + tid;              // wave-uniform base + l*16
      int row = c >> 2, slot = c & 3;
      int swz = (row ^ (row >> 2)) & 3;
      int gcol = k0 + ((slot ^ swz) << 3);
      gl_lds16(xh + (size_t)(mb + row) * ND + gcol, As + c * 16);
      gl_lds16(eh + (size_t)(nb + row) * ND + gcol, Bs + c * 16);
    }
    __syncthreads();
    s16x8 af[4], bf_[4];
    int ko = l >> 4;
    #pragma unroll
    for (int m = 0; m < 4; ++m) {
      int r = wr * 64 + m * 16 + (l & 15);
      int swz = (r ^ (r >> 2)) & 3;
      af[m] = *(const s16x8*)(As + r * 64 + ((ko ^ swz) << 4));
    }
    #pragma unroll
    for (int n = 0; n < 4; ++n) {
      int r = wc * 64 + n * 16 + (l & 15);
      int swz = (r ^ (r >> 2)) & 3;
      bf_[n] = *(const s16x8*)(Bs + r * 64 + ((ko ^ swz) << 4));
    }
    #pragma unroll
    for (int m = 0; m < 4; ++m)
      #pragma unroll
      for (int n = 0; n < 4; ++n)
        acc[m][n] = __builtin_amdgcn_mfma_f32_16x16x32_bf16(af[m], bf_[n], acc[m][n], 0, 0, 0);
    __syncthreads();
  }

  // epilogue: d2 = xn + exn - 2*dot, quantize u8.  C-map: row=(l>>4)*4+j, col=l&15
  int col0 = nb + wc * 64 + (l & 15);
  int row0 = mb + wr * 64 + (l >> 4) * 4;
  float exnv[4];
  #pragma unroll
  for (int n = 0; n < 4; ++n) exnv[n] = exn[col0 + n * 16];
  #pragma unroll
  for (int m = 0; m < 4; ++m) {
    #pragma unroll
    for (int j = 0; j < 4; ++j) {
      int qrow = row0 + m * 16 + j;
      float xq = xn[qrow];
      #pragma unroll
      for (int n = 0; n < 4; ++n) {
        float d2 = xq + exnv[n] - 2.f * acc[m][n][j];
        int bin = (int)floorf(d2 * QS);
        bin = bin < 0 ? 0 : (bin > 255 ? 255 : bin);
        d2q[(size_t)qrow * NE + (col0 + n * 16)] = (unsigned char)bin;
      }
    }
  }
}

// ---------------- K5: block-per-row exact top-K ----------------
// 256 threads per row: LDS histogram -> threshold bin (+1 guard) -> scan-compact
// -> 16-lane-group coalesced exact dots -> rank -> emit.
__global__ __launch_bounds__(256, 8) void k_select(
    const unsigned char* __restrict__ d2q,
    const float* __restrict__ x, const float* __restrict__ ex,
    const float* __restrict__ xn, const float* __restrict__ exn,
    float* __restrict__ selw, int* __restrict__ seli) {
  __shared__ unsigned int hist[256];
  __shared__ float4 xs[64];
  __shared__ int cand_e[NCAND];
  __shared__ float cand_d[NCAND];
  __shared__ unsigned int wsum[4];
  __shared__ int s_cb, s_nc;

  int tid = threadIdx.x;
  int l = tid & 63, w = tid >> 6;
  int b = blockIdx.x;

  // coalesced row load: 16 bytes/thread
  uint4 rb = reinterpret_cast<const uint4*>(d2q + (size_t)b * NE)[tid];
  if (tid < 64) xs[tid] = reinterpret_cast<const float4*>(x + (size_t)b * ND)[tid];
  hist[tid] = 0u;
  __syncthreads();

  unsigned int wd[4] = {rb.x, rb.y, rb.z, rb.w};
  #pragma unroll
  for (int c = 0; c < 4; ++c)
    #pragma unroll
    for (int k = 0; k < 4; ++k)
      atomicAdd(&hist[(wd[c] >> (8 * k)) & 255u], 1u);
  __syncthreads();

  // wave 0: prefix over 256 bins (4 per lane) -> smallest bin with cum >= NK
  if (w == 0) {
    unsigned int h0 = hist[l * 4], h1 = hist[l * 4 + 1], h2 = hist[l * 4 + 2], h3 = hist[l * 4 + 3];
    unsigned int gs = h0 + h1 + h2 + h3;
    unsigned int sc = gs;
    #pragma unroll
    for (int o = 1; o < 64; o <<= 1) { unsigned int v = __shfl_up(sc, o); if (l >= o) sc += v; }
    unsigned int excl = sc - gs;
    unsigned int c0 = excl + h0, c1 = c0 + h1, c2 = c1 + h2, c3 = c2 + h3;
    int local = (c0 >= (unsigned)NK) ? 0 : (c1 >= (unsigned)NK) ? 1
              : (c2 >= (unsigned)NK) ? 2 : (c3 >= (unsigned)NK) ? 3 : -1;
    unsigned long long ball = __ballot(local >= 0);
    int first = __ffsll((long long)ball) - 1;   // cum monotone -> first lane = smallest bin
    if (l == first) s_cb = l * 4 + local;
  }
  __syncthreads();
  int cbg = s_cb < 255 ? s_cb + 1 : 255;   // +1-bin guard band

  // scan-compact candidates (bin <= cbg), ascending element order
  int myc = 0;
  #pragma unroll
  for (int c = 0; c < 4; ++c)
    #pragma unroll
    for (int k = 0; k < 4; ++k)
      myc += ((int)((wd[c] >> (8 * k)) & 255u) <= cbg) ? 1 : 0;
  int sc = myc;
  #pragma unroll
  for (int o = 1; o < 64; o <<= 1) { int v = __shfl_up(sc, o); if (l >= o) sc += v; }
  if (l == 63) wsum[w] = (unsigned)sc;
  __syncthreads();
  int base = 0;
  for (int i = 0; i < w; ++i) base += (int)wsum[i];
  int slot = base + sc - myc;   // exclusive
  #pragma unroll
  for (int c = 0; c < 4; ++c)
    #pragma unroll
    for (int k = 0; k < 4; ++k) {
      int bin = (int)((wd[c] >> (8 * k)) & 255u);
      if (bin <= cbg) {
        if (slot < NCAND) cand_e[slot] = tid * 16 + c * 4 + k;
        ++slot;
      }
    }
  if (tid == 255) s_nc = (base + sc) < NCAND ? (base + sc) : NCAND;
  __syncthreads();

  int nc = s_nc;
  // exact fp32 dots: one candidate per 16-lane group; coalesced 256B loads per group
  float bxn = xn[b];
  int g = tid >> 4, gj = tid & 15;
  for (int c = g; c < nc; c += 16) {
    int e = cand_e[c];
    const float4* ep = reinterpret_cast<const float4*>(ex + (size_t)e * ND);
    float s = 0.f;
    #pragma unroll
    for (int it = 0; it < 4; ++it) {
      float4 xv = xs[gj + 16 * it];
      float4 evv = ep[gj + 16 * it];
      s += xv.x * evv.x + xv.y * evv.y + xv.z * evv.z + xv.w * evv.w;
    }
    s += __shfl_xor(s, 1, 16);
    s += __shfl_xor(s, 2, 16);
    s += __shfl_xor(s, 4, 16);
    s += __shfl_xor(s, 8, 16);
    if (gj == 0) cand_d[c] = bxn + exn[e] - 2.f * s;
  }
  __syncthreads();

  // rank among candidates (ascending cand_e => index tie-break == top_k)
  for (int i = tid; i < nc; i += 256) {
    float di = cand_d[i];
    int rank = 0;
    for (int j = 0; j < nc; ++j) {
      float dj = cand_d[j];
      rank += (dj < di) || (dj == di && j < i);
    }
    if (rank < NK) {
      float sq = fmaxf(di, 0.f);
      float wgt = (sq <= TAUSQ) ? expf(-sq) : 0.f;
      selw[(size_t)b * NK + rank] = wgt;
      seli[(size_t)b * NK + rank] = cand_e[i];
    }
  }
  if (tid >= nc && tid < NK) {   // degenerate-safety fill
    selw[(size_t)b * NK + tid] = 0.f;
    seli[(size_t)b * NK + tid] = 0;
  }
}

// ---------------- K6: gather-accumulate numer/denom, write hazards ----------------
__global__ __launch_bounds__(256) void k_out(const float* __restrict__ EV, const float* __restrict__ AR,
                                             const float* __restrict__ bev, const float* __restrict__ bar,
                                             const float* __restrict__ selw, const int* __restrict__ seli,
                                             float* __restrict__ out) {
  __shared__ float wl[NK];
  __shared__ int il[NK];
  __shared__ float den[NT];
  __shared__ float num[NT * NR];
  int tid = threadIdx.x;
  int b = blockIdx.x;
  if (tid < NK) { wl[tid] = selw[(size_t)b * NK + tid]; il[tid] = seli[(size_t)b * NK + tid]; }
  __syncthreads();
  float n0 = 0.f, n1 = 0.f, dn = 0.f;
  for (int k = 0; k < NK; ++k) {
    float wgt = wl[k];
    int e = il[k];
    const float* evp = EV + (size_t)e * (NT * NR);
    n0 += wgt * evp[tid];
    n1 += wgt * evp[256 + tid];
    if (tid < NT) dn += wgt * AR[(size_t)e * NT + tid];   // wave-uniform predicate
  }
  n0 += bev[tid];
  n1 += bev[256 + tid];
  num[tid] = n0; num[256 + tid] = n1;
  if (tid < NT) den[tid] = dn + bar[tid] + FEPS;
  __syncthreads();
  const float lo = FEPS, hi = 1.0f - FEPS;
  {
    int t = tid >> 2, r = tid & 3;                 // EV layout: f = t*4 + r
    float h = n0 / den[t];
    h = fminf(fmaxf(h, lo), hi);
    out[((size_t)r * NB + b) * NT + t] = h;        // esh[r][b][t]
    int f1 = tid + 256;
    int t1 = f1 >> 2, r1 = f1 & 3;
    float h1 = n1 / den[t1];
    h1 = fminf(fmaxf(h1, lo), hi);
    out[((size_t)r1 * NB + b) * NT + t1] = h1;
  }
  if (tid < NT) {
    float sum = num[4 * tid] + num[4 * tid + 1] + num[4 * tid + 2] + num[4 * tid + 3];
    float ov = sum / den[tid];
    ov = fminf(fmaxf(ov, lo), hi);
    out[(size_t)4 * NB * NT + (size_t)b * NT + tid] = ov;   // overall[b][t]
  }
}

} // namespace

extern "C" void kernel_launch(void* const* d_in, const int* in_sizes, int n_in,
                              void* d_out, int out_size, void* d_ws, size_t ws_size,
                              hipStream_t stream) {
  (void)in_sizes; (void)n_in; (void)out_size; (void)ws_size;
  const float* x     = (const float*)d_in[0];
  const float* ex    = (const float*)d_in[1];
  const float* lev   = (const float*)d_in[2];
  const float* lcen  = (const float*)d_in[3];
  const float* lbev  = (const float*)d_in[4];
  const float* lbcen = (const float*)d_in[5];
  float* out = (float*)d_out;

  // workspace layout (~53 MiB)
  char* ws = (char*)d_ws;
  float* EV  = (float*)(ws);                                      // [E][T][R]  8 MiB
  float* AR  = (float*)(ws + (8ull << 20));                       // [E][T]     2 MiB
  float* bev = (float*)(ws + (10ull << 20));                      // [T][R]
  float* bar = (float*)(ws + (10ull << 20) + 4096);               // [T]
  float* exn = (float*)(ws + (10ull << 20) + 8192);               // [E]
  float* xn  = (float*)(ws + (10ull << 20) + 8192 + (16u << 10)); // [B]
  unsigned char* d2q = (unsigned char*)(ws + (11ull << 20));      // [B][E] u8  32 MiB
  float* selw = (float*)(ws + (43ull << 20));                     // [B][K]     2 MiB
  int*   seli = (int*)  (ws + (45ull << 20));                     // [B][K]     2 MiB
  unsigned short* xh = (unsigned short*)(ws + (47ull << 20));     // [B][D] bf16 4 MiB
  unsigned short* eh = (unsigned short*)(ws + (51ull << 20));     // [E][D] bf16 2 MiB

  k_prep_base<<<1, NT, 0, stream>>>(lbev, lbcen, bev, bar);
  k_prep_ev<<<NE, NT, 0, stream>>>(lev, lcen, EV, AR);
  k_split<<<NB + NE, 64, 0, stream>>>(x, ex, xh, eh, xn, exn);
  k_dist_mfma<<<dim3(NE / 128, NB / 128), 256, 0, stream>>>(xh, eh, xn, exn, d2q);
  k_select<<<NB, 256, 0, stream>>>(d2q, x, ex, xn, exn, selw, seli);
  k_out<<<NB, 256, 0, stream>>>(EV, AR, bev, bar, selw, seli, out);
}

// Round 5
// 235.192 us; speedup vs baseline: 1.7475x; 1.1907x over previous
//
#include <hip/hip_runtime.h>
#include <hip/hip_fp16.h>
#include <math.h>

namespace {

constexpr int NB = 8192;   // batch B
constexpr int NE = 4096;   // exemplars E
constexpr int ND = 256;    // dim D
constexpr int NT = 128;    // time T
constexpr int NR = 4;      // risks R
constexpr int NK = 64;     // neighbors K
constexpr int NCAND = 320; // candidate cap per row
constexpr float TAUSQ = 4.0f;
constexpr float FEPS = 1e-12f;
constexpr float QS = 256.0f / 4.5f;   // u8 quantization over [0, 4.5)

typedef short s16x8 __attribute__((ext_vector_type(8)));
typedef float f32x4 __attribute__((ext_vector_type(4)));

__device__ __forceinline__ unsigned short f2bf_rne(float f) {
  unsigned int u = __float_as_uint(f);
  unsigned int r = (u + 0x7FFFu + ((u >> 16) & 1u)) >> 16;
  return (unsigned short)r;
}
__device__ __forceinline__ unsigned short f2h(float f) {
  return __half_as_ushort(__float2half(f));
}
__device__ __forceinline__ float h2f(unsigned short s) {
  return __half2float(__ushort_as_half(s));
}

__device__ __forceinline__ void gl_lds16(const void* g, void* lds) {
  __builtin_amdgcn_global_load_lds(
      (const __attribute__((address_space(1))) unsigned int*)g,
      (__attribute__((address_space(3))) unsigned int*)lds, 16, 0, 0);
}

// ---------------- K1: baseline prep (1 block, 128 thr) ----------------
__global__ void k_prep_base(const float* __restrict__ lbev, const float* __restrict__ lbcen,
                            float* __restrict__ bev, float* __restrict__ bar) {
  __shared__ float s[NT];
  int t = threadIdx.x;
  float acc = expf(lbcen[t]);
  for (int r = 0; r < NR; ++r) {
    float v = expf(lbev[t * NR + r]);
    bev[t * NR + r] = v;
    acc += v;
  }
  s[t] = acc;
  __syncthreads();
  float su = 0.f;
  for (int u = t; u < NT; ++u) su += s[u];   // reverse cumsum
  bar[t] = su;
}

// ---------------- K2: EVh = fp16(exp(log_ev)), ARh = fp16(rev-cumsum) ----------------
__global__ void k_prep_ev(const float* __restrict__ lev, const float* __restrict__ lcen,
                          unsigned short* __restrict__ EVh, unsigned short* __restrict__ ARh) {
  __shared__ float s[NT];
  int e = blockIdx.x, t = threadIdx.x;
  float acc = expf(lcen[(size_t)e * NT + t]);
  const float* src = lev + ((size_t)e * NT + t) * NR;
  float o0 = expf(src[0]), o1 = expf(src[1]), o2 = expf(src[2]), o3 = expf(src[3]);
  ushort4 h4;
  h4.x = f2h(o0); h4.y = f2h(o1); h4.z = f2h(o2); h4.w = f2h(o3);
  *reinterpret_cast<ushort4*>(EVh + ((size_t)e * NT + t) * NR) = h4;
  acc += o0 + o1 + o2 + o3;
  s[t] = acc;
  __syncthreads();
  float su = 0.f;
  for (int u = t; u < NT; ++u) su += s[u];
  ARh[(size_t)e * NT + t] = f2h(su);
}

// ---------------- K3: bf16 convert + row norms (grid B+E, 1 wave) ----------------
__global__ void k_split(const float* __restrict__ x, const float* __restrict__ ex,
                        unsigned short* __restrict__ xh, unsigned short* __restrict__ eh,
                        float* __restrict__ xn, float* __restrict__ exn) {
  int row = blockIdx.x, l = threadIdx.x;  // 64 threads, 4 floats each
  bool isx = row < NB;
  const float* p = isx ? (x + (size_t)row * ND) : (ex + (size_t)(row - NB) * ND);
  unsigned short* dst = isx ? (xh + (size_t)row * ND) : (eh + (size_t)(row - NB) * ND);
  float4 v = reinterpret_cast<const float4*>(p)[l];
  float nv = v.x * v.x + v.y * v.y + v.z * v.z + v.w * v.w;
  ushort4 h4;
  h4.x = f2bf_rne(v.x); h4.y = f2bf_rne(v.y);
  h4.z = f2bf_rne(v.z); h4.w = f2bf_rne(v.w);
  reinterpret_cast<ushort4*>(dst)[l] = h4;
  for (int o = 32; o > 0; o >>= 1) nv += __shfl_down(nv, o);
  if (l == 0) { if (isx) xn[row] = nv; else exn[row - NB] = nv; }
}

// ---------------- K4: bf16 MFMA distance GEMM (K=256) -> u8 bins ----------------
// 128x128 tile, 4 waves (2x2), 16x16x32 bf16 MFMA, global_load_lds + XOR swizzle.
__global__ __launch_bounds__(256) void k_dist_mfma(
    const unsigned short* __restrict__ xh, const unsigned short* __restrict__ eh,
    const float* __restrict__ xn, const float* __restrict__ exn,
    unsigned char* __restrict__ d2q) {
  __shared__ __align__(16) unsigned char As[128 * 64];  // 128 rows x 32 bf16 (64 B/row)
  __shared__ __align__(16) unsigned char Bs[128 * 64];
  int tid = threadIdx.x;
  int l = tid & 63, w = tid >> 6;
  int wr = w >> 1, wc = w & 1;
  int nb = blockIdx.x * 128, mb = blockIdx.y * 128;

  f32x4 acc[4][4];
  #pragma unroll
  for (int m = 0; m < 4; ++m)
    #pragma unroll
    for (int n = 0; n < 4; ++n)
      acc[m][n] = (f32x4){0.f, 0.f, 0.f, 0.f};

  for (int k0 = 0; k0 < ND; k0 += 32) {
    // stage: 512 chunks of 16 B per tile; chunk c -> row=c>>2, lds-slot=c&3.
    // linear LDS dest + pre-swizzled global source (slot ^ swz(row))
    #pragma unroll
    for (int h = 0; h < 2; ++h) {
      int c = h * 256 + tid;              // wave-uniform base + l*16
      int row = c >> 2, slot = c & 3;
      int swz = (row ^ (row >> 2)) & 3;
      int gcol = k0 + ((slot ^ swz) << 3);
      gl_lds16(xh + (size_t)(mb + row) * ND + gcol, As + c * 16);
      gl_lds16(eh + (size_t)(nb + row) * ND + gcol, Bs + c * 16);
    }
    __syncthreads();
    s16x8 af[4], bf_[4];
    int ko = l >> 4;
    #pragma unroll
    for (int m = 0; m < 4; ++m) {
      int r = wr * 64 + m * 16 + (l & 15);
      int swz = (r ^ (r >> 2)) & 3;
      af[m] = *(const s16x8*)(As + r * 64 + ((ko ^ swz) << 4));
    }
    #pragma unroll
    for (int n = 0; n < 4; ++n) {
      int r = wc * 64 + n * 16 + (l & 15);
      int swz = (r ^ (r >> 2)) & 3;
      bf_[n] = *(const s16x8*)(Bs + r * 64 + ((ko ^ swz) << 4));
    }
    #pragma unroll
    for (int m = 0; m < 4; ++m)
      #pragma unroll
      for (int n = 0; n < 4; ++n)
        acc[m][n] = __builtin_amdgcn_mfma_f32_16x16x32_bf16(af[m], bf_[n], acc[m][n], 0, 0, 0);
    __syncthreads();
  }

  // epilogue: d2 = xn + exn - 2*dot, quantize u8.  C-map: row=(l>>4)*4+j, col=l&15
  int col0 = nb + wc * 64 + (l & 15);
  int row0 = mb + wr * 64 + (l >> 4) * 4;
  float exnv[4];
  #pragma unroll
  for (int n = 0; n < 4; ++n) exnv[n] = exn[col0 + n * 16];
  #pragma unroll
  for (int m = 0; m < 4; ++m) {
    #pragma unroll
    for (int j = 0; j < 4; ++j) {
      int qrow = row0 + m * 16 + j;
      float xq = xn[qrow];
      #pragma unroll
      for (int n = 0; n < 4; ++n) {
        float d2 = xq + exnv[n] - 2.f * acc[m][n][j];
        int bin = (int)floorf(d2 * QS);
        bin = bin < 0 ? 0 : (bin > 255 ? 255 : bin);
        d2q[(size_t)qrow * NE + (col0 + n * 16)] = (unsigned char)bin;
      }
    }
  }
}

// ---------------- K5: block-per-row exact top-K ----------------
// 256 threads per row: LDS histogram -> threshold bin (+1 guard) -> scan-compact
// -> 16-lane-group coalesced exact dots -> rank -> emit.
__global__ __launch_bounds__(256, 8) void k_select(
    const unsigned char* __restrict__ d2q,
    const float* __restrict__ x, const float* __restrict__ ex,
    const float* __restrict__ xn, const float* __restrict__ exn,
    float* __restrict__ selw, int* __restrict__ seli) {
  __shared__ unsigned int hist[256];
  __shared__ float4 xs[64];
  __shared__ int cand_e[NCAND];
  __shared__ float cand_d[NCAND];
  __shared__ unsigned int wsum[4];
  __shared__ int s_cb, s_nc;

  int tid = threadIdx.x;
  int l = tid & 63, w = tid >> 6;
  int b = blockIdx.x;

  // coalesced row load: 16 bytes/thread
  uint4 rb = reinterpret_cast<const uint4*>(d2q + (size_t)b * NE)[tid];
  if (tid < 64) xs[tid] = reinterpret_cast<const float4*>(x + (size_t)b * ND)[tid];
  hist[tid] = 0u;
  __syncthreads();

  unsigned int wd[4] = {rb.x, rb.y, rb.z, rb.w};
  #pragma unroll
  for (int c = 0; c < 4; ++c)
    #pragma unroll
    for (int k = 0; k < 4; ++k)
      atomicAdd(&hist[(wd[c] >> (8 * k)) & 255u], 1u);
  __syncthreads();

  // wave 0: prefix over 256 bins (4 per lane) -> smallest bin with cum >= NK
  if (w == 0) {
    unsigned int h0 = hist[l * 4], h1 = hist[l * 4 + 1], h2 = hist[l * 4 + 2], h3 = hist[l * 4 + 3];
    unsigned int gs = h0 + h1 + h2 + h3;
    unsigned int sc = gs;
    #pragma unroll
    for (int o = 1; o < 64; o <<= 1) { unsigned int v = __shfl_up(sc, o); if (l >= o) sc += v; }
    unsigned int excl = sc - gs;
    unsigned int c0 = excl + h0, c1 = c0 + h1, c2 = c1 + h2, c3 = c2 + h3;
    int local = (c0 >= (unsigned)NK) ? 0 : (c1 >= (unsigned)NK) ? 1
              : (c2 >= (unsigned)NK) ? 2 : (c3 >= (unsigned)NK) ? 3 : -1;
    unsigned long long ball = __ballot(local >= 0);
    int first = __ffsll((long long)ball) - 1;   // cum monotone -> first lane = smallest bin
    if (l == first) s_cb = l * 4 + local;
  }
  __syncthreads();
  int cbg = s_cb < 255 ? s_cb + 1 : 255;   // +1-bin guard band

  // scan-compact candidates (bin <= cbg), ascending element order
  int myc = 0;
  #pragma unroll
  for (int c = 0; c < 4; ++c)
    #pragma unroll
    for (int k = 0; k < 4; ++k)
      myc += ((int)((wd[c] >> (8 * k)) & 255u) <= cbg) ? 1 : 0;
  int sc = myc;
  #pragma unroll
  for (int o = 1; o < 64; o <<= 1) { int v = __shfl_up(sc, o); if (l >= o) sc += v; }
  if (l == 63) wsum[w] = (unsigned)sc;
  __syncthreads();
  int base = 0;
  for (int i = 0; i < w; ++i) base += (int)wsum[i];
  int slot = base + sc - myc;   // exclusive
  #pragma unroll
  for (int c = 0; c < 4; ++c)
    #pragma unroll
    for (int k = 0; k < 4; ++k) {
      int bin = (int)((wd[c] >> (8 * k)) & 255u);
      if (bin <= cbg) {
        if (slot < NCAND) cand_e[slot] = tid * 16 + c * 4 + k;
        ++slot;
      }
    }
  if (tid == 255) s_nc = (base + sc) < NCAND ? (base + sc) : NCAND;
  __syncthreads();

  int nc = s_nc;
  // exact fp32 dots: one candidate per 16-lane group; coalesced 256B loads per group
  float bxn = xn[b];
  int g = tid >> 4, gj = tid & 15;
  for (int c = g; c < nc; c += 16) {
    int e = cand_e[c];
    const float4* ep = reinterpret_cast<const float4*>(ex + (size_t)e * ND);
    float s = 0.f;
    #pragma unroll
    for (int it = 0; it < 4; ++it) {
      float4 xv = xs[gj + 16 * it];
      float4 evv = ep[gj + 16 * it];
      s += xv.x * evv.x + xv.y * evv.y + xv.z * evv.z + xv.w * evv.w;
    }
    s += __shfl_xor(s, 1, 16);
    s += __shfl_xor(s, 2, 16);
    s += __shfl_xor(s, 4, 16);
    s += __shfl_xor(s, 8, 16);
    if (gj == 0) cand_d[c] = bxn + exn[e] - 2.f * s;
  }
  __syncthreads();

  // rank among candidates (ascending cand_e => index tie-break == top_k)
  for (int i = tid; i < nc; i += 256) {
    float di = cand_d[i];
    int rank = 0;
    for (int j = 0; j < nc; ++j) {
      float dj = cand_d[j];
      rank += (dj < di) || (dj == di && j < i);
    }
    if (rank < NK) {
      float sq = fmaxf(di, 0.f);
      float wgt = (sq <= TAUSQ) ? expf(-sq) : 0.f;
      selw[(size_t)b * NK + rank] = wgt;
      seli[(size_t)b * NK + rank] = cand_e[i];
    }
  }
  if (tid >= nc && tid < NK) {   // degenerate-safety fill
    selw[(size_t)b * NK + tid] = 0.f;
    seli[(size_t)b * NK + tid] = 0;
  }
}

// ---------------- K6: fp16 gather-accumulate numer/denom, write hazards ----------------
// 2 EV rows per iteration: 128 threads/row, 8 B/lane ushort4 loads (512 B/wave).
__global__ __launch_bounds__(256) void k_out(
    const unsigned short* __restrict__ EVh, const unsigned short* __restrict__ ARh,
    const float* __restrict__ bev, const float* __restrict__ bar,
    const float* __restrict__ selw, const int* __restrict__ seli,
    float* __restrict__ out) {
  __shared__ float wl[NK];
  __shared__ int il[NK];
  __shared__ float snum[NT * NR];
  __shared__ float sden[NT];
  int tid = threadIdx.x;
  int b = blockIdx.x;
  if (tid < NK) { wl[tid] = selw[(size_t)b * NK + tid]; il[tid] = seli[(size_t)b * NK + tid]; }
  __syncthreads();

  int g = tid >> 7;        // group 0: even k, group 1: odd k
  int t = tid & 127;
  float acc0 = 0.f, acc1 = 0.f, acc2 = 0.f, acc3 = 0.f, dacc = 0.f;
  for (int k = g; k < NK; k += 2) {
    float wgt = wl[k];
    int e = il[k];
    ushort4 v = reinterpret_cast<const ushort4*>(EVh + (size_t)e * (NT * NR))[t];
    acc0 += wgt * h2f(v.x);
    acc1 += wgt * h2f(v.y);
    acc2 += wgt * h2f(v.z);
    acc3 += wgt * h2f(v.w);
    dacc += wgt * h2f(ARh[(size_t)e * NT + t]);
  }
  if (g == 0) {
    snum[t * 4 + 0] = acc0; snum[t * 4 + 1] = acc1;
    snum[t * 4 + 2] = acc2; snum[t * 4 + 3] = acc3;
    sden[t] = dacc;
  }
  __syncthreads();
  if (g == 1) {
    snum[t * 4 + 0] += acc0 + bev[t * 4 + 0];
    snum[t * 4 + 1] += acc1 + bev[t * 4 + 1];
    snum[t * 4 + 2] += acc2 + bev[t * 4 + 2];
    snum[t * 4 + 3] += acc3 + bev[t * 4 + 3];
    sden[t] += dacc + bar[t] + FEPS;
  }
  __syncthreads();

  const float lo = FEPS, hi = 1.0f - FEPS;
  {
    int f = tid;
    int tt = f >> 2, r = f & 3;
    float h = snum[f] / sden[tt];
    h = fminf(fmaxf(h, lo), hi);
    out[((size_t)r * NB + b) * NT + tt] = h;       // esh[r][b][t]
    int f1 = tid + 256;
    int t1 = f1 >> 2, r1 = f1 & 3;
    float h1 = snum[f1] / sden[t1];
    h1 = fminf(fmaxf(h1, lo), hi);
    out[((size_t)r1 * NB + b) * NT + t1] = h1;
  }
  if (tid < NT) {
    float sum = snum[4 * tid] + snum[4 * tid + 1] + snum[4 * tid + 2] + snum[4 * tid + 3];
    float ov = sum / sden[tid];
    ov = fminf(fmaxf(ov, lo), hi);
    out[(size_t)4 * NB * NT + (size_t)b * NT + tid] = ov;   // overall[b][t]
  }
}

} // namespace

extern "C" void kernel_launch(void* const* d_in, const int* in_sizes, int n_in,
                              void* d_out, int out_size, void* d_ws, size_t ws_size,
                              hipStream_t stream) {
  (void)in_sizes; (void)n_in; (void)out_size; (void)ws_size;
  const float* x     = (const float*)d_in[0];
  const float* ex    = (const float*)d_in[1];
  const float* lev   = (const float*)d_in[2];
  const float* lcen  = (const float*)d_in[3];
  const float* lbev  = (const float*)d_in[4];
  const float* lbcen = (const float*)d_in[5];
  float* out = (float*)d_out;

  // workspace layout (~48 MiB)
  char* ws = (char*)d_ws;
  unsigned short* EVh = (unsigned short*)(ws);                    // [E][T][R] fp16  4 MiB
  unsigned short* ARh = (unsigned short*)(ws + (4ull << 20));     // [E][T]    fp16  1 MiB
  float* bev = (float*)(ws + (5ull << 20));                       // [T][R]
  float* bar = (float*)(ws + (5ull << 20) + 4096);                // [T]
  float* exn = (float*)(ws + (5ull << 20) + 8192);                // [E]
  float* xn  = (float*)(ws + (5ull << 20) + 8192 + (16u << 10));  // [B]
  unsigned char* d2q = (unsigned char*)(ws + (6ull << 20));       // [B][E] u8  32 MiB
  float* selw = (float*)(ws + (38ull << 20));                     // [B][K]     2 MiB
  int*   seli = (int*)  (ws + (40ull << 20));                     // [B][K]     2 MiB
  unsigned short* xh = (unsigned short*)(ws + (42ull << 20));     // [B][D] bf16 4 MiB
  unsigned short* eh = (unsigned short*)(ws + (46ull << 20));     // [E][D] bf16 2 MiB

  k_prep_base<<<1, NT, 0, stream>>>(lbev, lbcen, bev, bar);
  k_prep_ev<<<NE, NT, 0, stream>>>(lev, lcen, EVh, ARh);
  k_split<<<NB + NE, 64, 0, stream>>>(x, ex, xh, eh, xn, exn);
  k_dist_mfma<<<dim3(NE / 128, NB / 128), 256, 0, stream>>>(xh, eh, xn, exn, d2q);
  k_select<<<NB, 256, 0, stream>>>(d2q, x, ex, xn, exn, selw, seli);
  k_out<<<NB, 256, 0, stream>>>(EVh, ARh, bev, bar, selw, seli, out);
}

// Round 7
// 212.999 us; speedup vs baseline: 1.9296x; 1.1042x over previous
//
#include <hip/hip_runtime.h>
#include <hip/hip_fp16.h>
#include <math.h>

namespace {

constexpr int NB = 8192;   // batch B
constexpr int NE = 4096;   // exemplars E
constexpr int ND = 256;    // dim D
constexpr int NT = 128;    // time T
constexpr int NR = 4;      // risks R
constexpr int NK = 64;     // neighbors K
constexpr int NCAND = 320; // candidate cap per row
constexpr float TAUSQ = 4.0f;
constexpr float FEPS = 1e-12f;
constexpr float QS = 256.0f / 4.5f;   // u8 quantization over [0, 4.5)

typedef short s16x8 __attribute__((ext_vector_type(8)));
typedef float f32x4 __attribute__((ext_vector_type(4)));

__device__ __forceinline__ unsigned short f2bf_rne(float f) {
  unsigned int u = __float_as_uint(f);
  unsigned int r = (u + 0x7FFFu + ((u >> 16) & 1u)) >> 16;
  return (unsigned short)r;
}
__device__ __forceinline__ unsigned short f2h(float f) {
  return __half_as_ushort(__float2half(f));
}
__device__ __forceinline__ float h2f(unsigned short s) {
  return __half2float(__ushort_as_half(s));
}

__device__ __forceinline__ void gl_lds16(const void* g, void* lds) {
  __builtin_amdgcn_global_load_lds(
      (const __attribute__((address_space(1))) unsigned int*)g,
      (__attribute__((address_space(3))) unsigned int*)lds, 16, 0, 0);
}

// ---------------- K1: fused prep (grid NE+1, 128 thr) ----------------
// blocks 0..NE-1: EVh = fp16(exp(log_ev)), ARh = fp16(suffix-sum)
// block NE: baseline bev fp32, bar fp32 (suffix-sum)
__global__ void k_prep(const float* __restrict__ lev, const float* __restrict__ lcen,
                       const float* __restrict__ lbev, const float* __restrict__ lbcen,
                       unsigned short* __restrict__ EVh, unsigned short* __restrict__ ARh,
                       float* __restrict__ bev, float* __restrict__ bar) {
  __shared__ float wtot;
  int t = threadIdx.x, l = t & 63;
  int e = blockIdx.x;
  float acc;
  if (e < NE) {
    acc = expf(lcen[(size_t)e * NT + t]);
    const float* src = lev + ((size_t)e * NT + t) * NR;
    float o0 = expf(src[0]), o1 = expf(src[1]), o2 = expf(src[2]), o3 = expf(src[3]);
    ushort4 h4;
    h4.x = f2h(o0); h4.y = f2h(o1); h4.z = f2h(o2); h4.w = f2h(o3);
    *reinterpret_cast<ushort4*>(EVh + ((size_t)e * NT + t) * NR) = h4;
    acc += o0 + o1 + o2 + o3;
  } else {
    acc = expf(lbcen[t]);
    const float* src = lbev + t * NR;
    float o0 = expf(src[0]), o1 = expf(src[1]), o2 = expf(src[2]), o3 = expf(src[3]);
    bev[t * NR + 0] = o0; bev[t * NR + 1] = o1;
    bev[t * NR + 2] = o2; bev[t * NR + 3] = o3;
    acc += o0 + o1 + o2 + o3;
  }
  // 2-wave suffix-inclusive scan over 128 values
  float v = acc;
  #pragma unroll
  for (int o = 1; o < 64; o <<= 1) {
    float u = __shfl_down(v, o);
    if (l + o < 64) v += u;
  }
  if (t == 64) wtot = v;   // wave1 lane0 = sum of s[64..127]
  __syncthreads();
  if (t < 64) v += wtot;
  if (e < NE) ARh[(size_t)e * NT + t] = f2h(v);
  else        bar[t] = v;
}

// ---------------- K3: bf16 convert + row norms (grid B+E, 1 wave) ----------------
__global__ void k_split(const float* __restrict__ x, const float* __restrict__ ex,
                        unsigned short* __restrict__ xh, unsigned short* __restrict__ eh,
                        float* __restrict__ xn, float* __restrict__ exn) {
  int row = blockIdx.x, l = threadIdx.x;  // 64 threads, 4 floats each
  bool isx = row < NB;
  const float* p = isx ? (x + (size_t)row * ND) : (ex + (size_t)(row - NB) * ND);
  unsigned short* dst = isx ? (xh + (size_t)row * ND) : (eh + (size_t)(row - NB) * ND);
  float4 v = reinterpret_cast<const float4*>(p)[l];
  float nv = v.x * v.x + v.y * v.y + v.z * v.z + v.w * v.w;
  ushort4 h4;
  h4.x = f2bf_rne(v.x); h4.y = f2bf_rne(v.y);
  h4.z = f2bf_rne(v.z); h4.w = f2bf_rne(v.w);
  reinterpret_cast<ushort4*>(dst)[l] = h4;
  for (int o = 32; o > 0; o >>= 1) nv += __shfl_down(nv, o);
  if (l == 0) { if (isx) xn[row] = nv; else exn[row - NB] = nv; }
}

// ---------------- K4: bf16 MFMA distance GEMM (K=256, BK=64) -> u8 bins ----------------
// 128x128 tile, 4 waves (2x2), 16x16x32 bf16 MFMA, global_load_lds + XOR swizzle,
// bijective XCD swizzle on the flattened grid.
__global__ __launch_bounds__(256) void k_dist_mfma(
    const unsigned short* __restrict__ xh, const unsigned short* __restrict__ eh,
    const float* __restrict__ xn, const float* __restrict__ exn,
    unsigned char* __restrict__ d2q) {
  __shared__ __align__(16) unsigned char As[128 * 128];  // 128 rows x 64 bf16 (128 B/row)
  __shared__ __align__(16) unsigned char Bs[128 * 128];
  int tid = threadIdx.x;
  int l = tid & 63, w = tid >> 6;
  int wr = w >> 1, wc = w & 1;

  // XCD-aware bijective swizzle: 2048 blocks, 8 XCDs, 256 per chunk
  int lid = blockIdx.x;
  int sl = (lid & 7) * 256 + (lid >> 3);
  int nb = (sl & 31) * 128;    // e-tile (32 tiles)
  int mb = (sl >> 5) * 128;    // b-tile (64 tiles)

  f32x4 acc[4][4];
  #pragma unroll
  for (int m = 0; m < 4; ++m)
    #pragma unroll
    for (int n = 0; n < 4; ++n)
      acc[m][n] = (f32x4){0.f, 0.f, 0.f, 0.f};

  for (int k0 = 0; k0 < ND; k0 += 64) {
    // stage 128 rows x 64 cols per matrix: 1024 chunks of 16B, 4 per thread.
    // linear LDS dest + pre-swizzled global source (slot ^ swz(row), 8 slots/row)
    #pragma unroll
    for (int h = 0; h < 4; ++h) {
      int c = h * 256 + tid;              // wave-uniform base + l*16
      int row = c >> 3, slot = c & 7;
      int swz = (row ^ (row >> 3)) & 7;
      int gcol = k0 + ((slot ^ swz) << 3);
      gl_lds16(xh + (size_t)(mb + row) * ND + gcol, As + c * 16);
      gl_lds16(eh + (size_t)(nb + row) * ND + gcol, Bs + c * 16);
    }
    __syncthreads();
    #pragma unroll
    for (int kk = 0; kk < 2; ++kk) {
      s16x8 af[4], bf_[4];
      int sl0 = kk * 4 + (l >> 4);
      #pragma unroll
      for (int m = 0; m < 4; ++m) {
        int r = wr * 64 + m * 16 + (l & 15);
        int swz = (r ^ (r >> 3)) & 7;
        af[m] = *(const s16x8*)(As + r * 128 + ((sl0 ^ swz) << 4));
      }
      #pragma unroll
      for (int n = 0; n < 4; ++n) {
        int r = wc * 64 + n * 16 + (l & 15);
        int swz = (r ^ (r >> 3)) & 7;
        bf_[n] = *(const s16x8*)(Bs + r * 128 + ((sl0 ^ swz) << 4));
      }
      #pragma unroll
      for (int m = 0; m < 4; ++m)
        #pragma unroll
        for (int n = 0; n < 4; ++n)
          acc[m][n] = __builtin_amdgcn_mfma_f32_16x16x32_bf16(af[m], bf_[n], acc[m][n], 0, 0, 0);
    }
    __syncthreads();
  }

  // epilogue: d2 = xn + exn - 2*dot, quantize u8.  C-map: row=(l>>4)*4+j, col=l&15
  int col0 = nb + wc * 64 + (l & 15);
  int row0 = mb + wr * 64 + (l >> 4) * 4;
  float exnv[4];
  #pragma unroll
  for (int n = 0; n < 4; ++n) exnv[n] = exn[col0 + n * 16];
  #pragma unroll
  for (int m = 0; m < 4; ++m) {
    #pragma unroll
    for (int j = 0; j < 4; ++j) {
      int qrow = row0 + m * 16 + j;
      float xq = xn[qrow];
      #pragma unroll
      for (int n = 0; n < 4; ++n) {
        float d2 = xq + exnv[n] - 2.f * acc[m][n][j];
        int bin = (int)floorf(d2 * QS);
        bin = bin < 0 ? 0 : (bin > 255 ? 255 : bin);
        d2q[(size_t)qrow * NE + (col0 + n * 16)] = (unsigned char)bin;
      }
    }
  }
}

// ---------------- K5: block-per-row exact top-K ----------------
// 256 threads per row: LDS histogram -> threshold bin (+1 guard) -> scan-compact
// -> 16-lane-group coalesced exact dots (2 candidates/iter) -> rank -> emit.
__global__ __launch_bounds__(256, 8) void k_select(
    const unsigned char* __restrict__ d2q,
    const float* __restrict__ x, const float* __restrict__ ex,
    const float* __restrict__ xn, const float* __restrict__ exn,
    float* __restrict__ selw, int* __restrict__ seli) {
  __shared__ unsigned int hist[256];
  __shared__ float4 xs[64];
  __shared__ int cand_e[NCAND];
  __shared__ float cand_d[NCAND];
  __shared__ unsigned int wsum[4];
  __shared__ int s_cb, s_nc;

  int tid = threadIdx.x;
  int l = tid & 63, w = tid >> 6;
  int b = blockIdx.x;

  // coalesced row load: 16 bytes/thread
  uint4 rb = reinterpret_cast<const uint4*>(d2q + (size_t)b * NE)[tid];
  if (tid < 64) xs[tid] = reinterpret_cast<const float4*>(x + (size_t)b * ND)[tid];
  hist[tid] = 0u;
  __syncthreads();

  unsigned int wd[4] = {rb.x, rb.y, rb.z, rb.w};
  #pragma unroll
  for (int c = 0; c < 4; ++c)
    #pragma unroll
    for (int k = 0; k < 4; ++k)
      atomicAdd(&hist[(wd[c] >> (8 * k)) & 255u], 1u);

  // hoist x-row fragments for the dot phase (loop-invariant)
  int g = tid >> 4, gj = tid & 15;
  float4 xr0 = xs[gj], xr1 = xs[gj + 16], xr2 = xs[gj + 32], xr3 = xs[gj + 48];
  __syncthreads();

  // wave 0: prefix over 256 bins (4 per lane) -> smallest bin with cum >= NK
  if (w == 0) {
    unsigned int h0 = hist[l * 4], h1 = hist[l * 4 + 1], h2 = hist[l * 4 + 2], h3 = hist[l * 4 + 3];
    unsigned int gs = h0 + h1 + h2 + h3;
    unsigned int sc = gs;
    #pragma unroll
    for (int o = 1; o < 64; o <<= 1) { unsigned int v = __shfl_up(sc, o); if (l >= o) sc += v; }
    unsigned int excl = sc - gs;
    unsigned int c0 = excl + h0, c1 = c0 + h1, c2 = c1 + h2, c3 = c2 + h3;
    int local = (c0 >= (unsigned)NK) ? 0 : (c1 >= (unsigned)NK) ? 1
              : (c2 >= (unsigned)NK) ? 2 : (c3 >= (unsigned)NK) ? 3 : -1;
    unsigned long long ball = __ballot(local >= 0);
    int first = __ffsll((long long)ball) - 1;   // cum monotone -> first lane = smallest bin
    if (l == first) s_cb = l * 4 + local;
  }
  __syncthreads();
  int cbg = s_cb < 255 ? s_cb + 1 : 255;   // +1-bin guard band

  // scan-compact candidates (bin <= cbg), ascending element order
  int myc = 0;
  #pragma unroll
  for (int c = 0; c < 4; ++c)
    #pragma unroll
    for (int k = 0; k < 4; ++k)
      myc += ((int)((wd[c] >> (8 * k)) & 255u) <= cbg) ? 1 : 0;
  int sc = myc;
  #pragma unroll
  for (int o = 1; o < 64; o <<= 1) { int v = __shfl_up(sc, o); if (l >= o) sc += v; }
  if (l == 63) wsum[w] = (unsigned)sc;
  __syncthreads();
  int base = 0;
  for (int i = 0; i < w; ++i) base += (int)wsum[i];
  int slot = base + sc - myc;   // exclusive
  #pragma unroll
  for (int c = 0; c < 4; ++c)
    #pragma unroll
    for (int k = 0; k < 4; ++k) {
      int bin = (int)((wd[c] >> (8 * k)) & 255u);
      if (bin <= cbg) {
        if (slot < NCAND) cand_e[slot] = tid * 16 + c * 4 + k;
        ++slot;
      }
    }
  if (tid == 255) s_nc = (base + sc) < NCAND ? (base + sc) : NCAND;
  __syncthreads();

  int nc = s_nc;
  // exact fp32 dots: one 16-lane group per candidate, 2 candidates per iteration
  float bxn = xn[b];
  for (int c = g; c < nc; c += 32) {
    int eA = cand_e[c];
    int has2 = (c + 16) < nc;
    int eB = has2 ? cand_e[c + 16] : eA;
    const float4* pA = reinterpret_cast<const float4*>(ex + (size_t)eA * ND);
    const float4* pB = reinterpret_cast<const float4*>(ex + (size_t)eB * ND);
    float4 a0 = pA[gj], a1 = pA[gj + 16], a2 = pA[gj + 32], a3 = pA[gj + 48];
    float4 b0 = pB[gj], b1 = pB[gj + 16], b2 = pB[gj + 32], b3 = pB[gj + 48];
    float sA = xr0.x * a0.x + xr0.y * a0.y + xr0.z * a0.z + xr0.w * a0.w
             + xr1.x * a1.x + xr1.y * a1.y + xr1.z * a1.z + xr1.w * a1.w
             + xr2.x * a2.x + xr2.y * a2.y + xr2.z * a2.z + xr2.w * a2.w
             + xr3.x * a3.x + xr3.y * a3.y + xr3.z * a3.z + xr3.w * a3.w;
    float sB = xr0.x * b0.x + xr0.y * b0.y + xr0.z * b0.z + xr0.w * b0.w
             + xr1.x * b1.x + xr1.y * b1.y + xr1.z * b1.z + xr1.w * b1.w
             + xr2.x * b2.x + xr2.y * b2.y + xr2.z * b2.z + xr2.w * b2.w
             + xr3.x * b3.x + xr3.y * b3.y + xr3.z * b3.z + xr3.w * b3.w;
    #pragma unroll
    for (int o = 1; o < 16; o <<= 1) {
      sA += __shfl_xor(sA, o, 16);
      sB += __shfl_xor(sB, o, 16);
    }
    if (gj == 0) {
      cand_d[c] = bxn + exn[eA] - 2.f * sA;
      if (has2) cand_d[c + 16] = bxn + exn[eB] - 2.f * sB;
    }
  }
  __syncthreads();

  // rank among candidates (ascending cand_e => index tie-break == top_k)
  for (int i = tid; i < nc; i += 256) {
    float di = cand_d[i];
    int rank = 0;
    for (int j = 0; j < nc; ++j) {
      float dj = cand_d[j];
      rank += (dj < di) || (dj == di && j < i);
    }
    if (rank < NK) {
      float sq = fmaxf(di, 0.f);
      float wgt = (sq <= TAUSQ) ? expf(-sq) : 0.f;
      selw[(size_t)b * NK + rank] = wgt;
      seli[(size_t)b * NK + rank] = cand_e[i];
    }
  }
  if (tid >= nc && tid < NK) {   // degenerate-safety fill
    selw[(size_t)b * NK + tid] = 0.f;
    seli[(size_t)b * NK + tid] = 0;
  }
}

// ---------------- K6: fp16 gather-accumulate numer/denom, write hazards ----------------
// 2 EV rows per iteration: 128 threads/row, 8 B/lane ushort4 loads (512 B/wave).
__global__ __launch_bounds__(256) void k_out(
    const unsigned short* __restrict__ EVh, const unsigned short* __restrict__ ARh,
    const float* __restrict__ bev, const float* __restrict__ bar,
    const float* __restrict__ selw, const int* __restrict__ seli,
    float* __restrict__ out) {
  __shared__ float wl[NK];
  __shared__ int il[NK];
  __shared__ float snum[NT * NR];
  __shared__ float sden[NT];
  int tid = threadIdx.x;
  int b = blockIdx.x;
  if (tid < NK) { wl[tid] = selw[(size_t)b * NK + tid]; il[tid] = seli[(size_t)b * NK + tid]; }
  __syncthreads();

  int g = tid >> 7;        // group 0: even k, group 1: odd k
  int t = tid & 127;
  float acc0 = 0.f, acc1 = 0.f, acc2 = 0.f, acc3 = 0.f, dacc = 0.f;
  for (int k = g; k < NK; k += 2) {
    float wgt = wl[k];
    int e = il[k];
    ushort4 v = reinterpret_cast<const ushort4*>(EVh + (size_t)e * (NT * NR))[t];
    acc0 += wgt * h2f(v.x);
    acc1 += wgt * h2f(v.y);
    acc2 += wgt * h2f(v.z);
    acc3 += wgt * h2f(v.w);
    dacc += wgt * h2f(ARh[(size_t)e * NT + t]);
  }
  if (g == 0) {
    snum[t * 4 + 0] = acc0; snum[t * 4 + 1] = acc1;
    snum[t * 4 + 2] = acc2; snum[t * 4 + 3] = acc3;
    sden[t] = dacc;
  }
  __syncthreads();
  if (g == 1) {
    snum[t * 4 + 0] += acc0 + bev[t * 4 + 0];
    snum[t * 4 + 1] += acc1 + bev[t * 4 + 1];
    snum[t * 4 + 2] += acc2 + bev[t * 4 + 2];
    snum[t * 4 + 3] += acc3 + bev[t * 4 + 3];
    sden[t] += dacc + bar[t] + FEPS;
  }
  __syncthreads();

  const float lo = FEPS, hi = 1.0f - FEPS;
  {
    int f = tid;
    int tt = f >> 2, r = f & 3;
    float h = snum[f] / sden[tt];
    h = fminf(fmaxf(h, lo), hi);
    out[((size_t)r * NB + b) * NT + tt] = h;       // esh[r][b][t]
    int f1 = tid + 256;
    int t1 = f1 >> 2, r1 = f1 & 3;
    float h1 = snum[f1] / sden[t1];
    h1 = fminf(fmaxf(h1, lo), hi);
    out[((size_t)r1 * NB + b) * NT + t1] = h1;
  }
  if (tid < NT) {
    float sum = snum[4 * tid] + snum[4 * tid + 1] + snum[4 * tid + 2] + snum[4 * tid + 3];
    float ov = sum / sden[tid];
    ov = fminf(fmaxf(ov, lo), hi);
    out[(size_t)4 * NB * NT + (size_t)b * NT + tid] = ov;   // overall[b][t]
  }
}

} // namespace

extern "C" void kernel_launch(void* const* d_in, const int* in_sizes, int n_in,
                              void* d_out, int out_size, void* d_ws, size_t ws_size,
                              hipStream_t stream) {
  (void)in_sizes; (void)n_in; (void)out_size; (void)ws_size;
  const float* x     = (const float*)d_in[0];
  const float* ex    = (const float*)d_in[1];
  const float* lev   = (const float*)d_in[2];
  const float* lcen  = (const float*)d_in[3];
  const float* lbev  = (const float*)d_in[4];
  const float* lbcen = (const float*)d_in[5];
  float* out = (float*)d_out;

  // workspace layout (~48 MiB)
  char* ws = (char*)d_ws;
  unsigned short* EVh = (unsigned short*)(ws);                    // [E][T][R] fp16  4 MiB
  unsigned short* ARh = (unsigned short*)(ws + (4ull << 20));     // [E][T]    fp16  1 MiB
  float* bev = (float*)(ws + (5ull << 20));                       // [T][R]
  float* bar = (float*)(ws + (5ull << 20) + 4096);                // [T]
  float* exn = (float*)(ws + (5ull << 20) + 8192);                // [E]
  float* xn  = (float*)(ws + (5ull << 20) + 8192 + (16u << 10));  // [B]
  unsigned char* d2q = (unsigned char*)(ws + (6ull << 20));       // [B][E] u8  32 MiB
  float* selw = (float*)(ws + (38ull << 20));                     // [B][K]     2 MiB
  int*   seli = (int*)  (ws + (40ull << 20));                     // [B][K]     2 MiB
  unsigned short* xh = (unsigned short*)(ws + (42ull << 20));     // [B][D] bf16 4 MiB
  unsigned short* eh = (unsigned short*)(ws + (46ull << 20));     // [E][D] bf16 2 MiB

  k_prep<<<NE + 1, NT, 0, stream>>>(lev, lcen, lbev, lbcen, EVh, ARh, bev, bar);
  k_split<<<NB + NE, 64, 0, stream>>>(x, ex, xh, eh, xn, exn);
  k_dist_mfma<<<2048, 256, 0, stream>>>(xh, eh, xn, exn, d2q);
  k_select<<<NB, 256, 0, stream>>>(d2q, x, ex, xn, exn, selw, seli);
  k_out<<<NB, 256, 0, stream>>>(EVh, ARh, bev, bar, selw, seli, out);
}